// Round 2
// baseline (6145.270 us; speedup 1.0000x reference)
//
#include <hip/hip_runtime.h>

#define N_NODES 100000
#define N_EDGES 1600000
#define NF 128
#define NC 16
#define NH 2
#define HC 32   // NH*NC
#define NL 2
#define NED 4
#define EPS 1e-5f
#define NEG 0.2f

// ---- bf16 helpers (manual, RTN-even) -----------------------------------------
__device__ __forceinline__ unsigned short f2bf(float f) {
    unsigned int u = __float_as_uint(f);
    u += 0x7fffu + ((u >> 16) & 1u);
    return (unsigned short)(u >> 16);
}
__device__ __forceinline__ void load_bf16x32(const unsigned short* p, float* out) {
    const uint4* q = (const uint4*)p;   // 64 B = 4 x 16 B vector loads
#pragma unroll
    for (int i = 0; i < 4; ++i) {
        uint4 u = q[i];
        unsigned int w[4] = {u.x, u.y, u.z, u.w};
#pragma unroll
        for (int k = 0; k < 4; ++k) {
            out[i * 8 + 2 * k]     = __uint_as_float(w[k] << 16);
            out[i * 8 + 2 * k + 1] = __uint_as_float(w[k] & 0xffff0000u);
        }
    }
}

// ---------------- embed: h = relu(node_LN(x @ W + b)) ; jk = h ----------------
__global__ __launch_bounds__(256) void k_embed(
    const float* __restrict__ x, const float* __restrict__ W,
    const float* __restrict__ b, const float* __restrict__ lnw,
    const float* __restrict__ lnb, float* __restrict__ h, float* __restrict__ jk)
{
    __shared__ float Ws[NF * NC];        // 8 KB
    __shared__ float xs[16][NF + 4];
    const int t = threadIdx.x;
    for (int i = t; i < NF * NC; i += 256) Ws[i] = W[i];
    const int n0 = blockIdx.x * 16;
    for (int i = t; i < 16 * NF; i += 256) {
        int r = i >> 7, f = i & (NF - 1);
        int n = n0 + r;
        xs[r][f] = (n < N_NODES) ? x[(size_t)n * NF + f] : 0.f;
    }
    __syncthreads();
    const int r = t >> 4;       // local node 0..15
    const int c = t & 15;       // channel
    const int n = n0 + r;
    float acc = b[c];
#pragma unroll 16
    for (int f = 0; f < NF; ++f) acc += xs[r][f] * Ws[f * NC + c];
    float s = acc;
    for (int m = 8; m >= 1; m >>= 1) s += __shfl_xor(s, m, 16);
    float mu = s * (1.f / 16.f);
    float d = acc - mu;
    float v = d * d;
    for (int m = 8; m >= 1; m >>= 1) v += __shfl_xor(v, m, 16);
    float inv = rsqrtf(v * (1.f / 16.f) + EPS);
    float out = fmaxf(d * inv * lnw[c] + lnb[c], 0.f);
    if (n < N_NODES) {
        h[(size_t)n * NC + c]  = out;
        jk[(size_t)n * NC + c] = out;
    }
}

// ---- per-layer: xl/xr transforms (bf16 out) + self-loop init of den/g --------
__global__ __launch_bounds__(256) void k_trans(
    const float* __restrict__ h, const float* __restrict__ Wl, const float* __restrict__ bl,
    const float* __restrict__ Wr, const float* __restrict__ br,
    const float* __restrict__ att,
    unsigned short* __restrict__ xl, unsigned short* __restrict__ xr,
    float* __restrict__ den, float* __restrict__ g)
{
    __shared__ float Wls[NC * HC], Wrs[NC * HC];
    __shared__ float atts[HC];
    __shared__ float hs[8][NC + 1];
    const int t = threadIdx.x;
    for (int i = t; i < NC * HC; i += 256) { Wls[i] = Wl[i]; Wrs[i] = Wr[i]; }
    if (t < HC) atts[t] = att[t];
    const int n0 = blockIdx.x * 8;
    for (int i = t; i < 8 * NC; i += 256) {
        int r = i >> 4, c = i & 15;
        int n = n0 + r;
        hs[r][c] = (n < N_NODES) ? h[(size_t)n * NC + c] : 0.f;
    }
    __syncthreads();
    const int r = t >> 5;     // local node 0..7
    const int j = t & 31;     // output col (head*16 + c)
    const int n = n0 + r;
    float al = bl[j], ar = br[j];
#pragma unroll
    for (int c = 0; c < NC; ++c) {
        float hv = hs[r][c];
        al += hv * Wls[c * HC + j];
        ar += hv * Wrs[c * HC + j];
    }
    // self-loop edge (src=dst=n, ew=0): logit per head via 16-lane reduce
    float m = al + ar;
    m = (m > 0.f) ? m : NEG * m;
    float p = m * atts[j];
    for (int k = 8; k >= 1; k >>= 1) p += __shfl_xor(p, k, 16);
    float exs = __expf(p);
    if (n < N_NODES) {
        xl[(size_t)n * HC + j] = f2bf(al);
        xr[(size_t)n * HC + j] = f2bf(ar);
        g[(size_t)n * HC + j]  = exs * al;          // init: self contribution
        if ((j & 15) == 0) den[(size_t)n * 2 + (j >> 4)] = exs;
    }
}

// ---- fused edge pass: logits -> ex ; den += ex ; g += ex * xl[src] -----------
__global__ __launch_bounds__(256) void k_edge(
    const int* __restrict__ src, const int* __restrict__ dst,
    const float* __restrict__ eattr, const float* __restrict__ We,
    const float* __restrict__ att,
    const unsigned short* __restrict__ xl, const unsigned short* __restrict__ xr,
    float* __restrict__ den, float* __restrict__ g)
{
    __shared__ float Wes[NED * HC];
    __shared__ float atts[HC];
    const int t = threadIdx.x;
    if (t < NED * HC) Wes[t] = We[t];
    if (t < HC) atts[t] = att[t];
    __syncthreads();
    const int e = blockIdx.x * 256 + t;
    if (e >= N_EDGES) return;
    const int s = src[e], d = dst[e];
    float4 ea = *(const float4*)(eattr + (size_t)e * 4);
    float xlv[HC], xrv[HC];
    load_bf16x32(xl + (size_t)s * HC, xlv);
    load_bf16x32(xr + (size_t)d * HC, xrv);
    float acc0 = 0.f, acc1 = 0.f;
#pragma unroll
    for (int c = 0; c < NC; ++c) {
        float ewv = ea.x * Wes[c] + ea.y * Wes[HC + c] + ea.z * Wes[2 * HC + c] + ea.w * Wes[3 * HC + c];
        float m = xlv[c] + xrv[c] + ewv;
        m = (m > 0.f) ? m : NEG * m;
        acc0 += m * atts[c];
    }
#pragma unroll
    for (int c = 0; c < NC; ++c) {
        int j = NC + c;
        float ewv = ea.x * Wes[j] + ea.y * Wes[HC + j] + ea.z * Wes[2 * HC + j] + ea.w * Wes[3 * HC + j];
        float m = xlv[j] + xrv[j] + ewv;
        m = (m > 0.f) ? m : NEG * m;
        acc1 += m * atts[j];
    }
    // logits tiny (std ~0.16): exp without segment-max is numerically identical
    float e0 = __expf(acc0), e1 = __expf(acc1);
    atomicAdd(&den[(size_t)d * 2 + 0], e0);
    atomicAdd(&den[(size_t)d * 2 + 1], e1);
    float* gr = g + (size_t)d * HC;
#pragma unroll
    for (int c = 0; c < NC; ++c) atomicAdd(&gr[c], e0 * xlv[c]);
#pragma unroll
    for (int c = 0; c < NC; ++c) atomicAdd(&gr[NC + c], e1 * xlv[NC + c]);
}

// ---- graph-LN stats over (g/den + gat_b) -------------------------------------
__global__ __launch_bounds__(256) void k_stats1(
    const float* __restrict__ g, const float* __restrict__ den,
    const float* __restrict__ gat_b, double* __restrict__ stats)
{
    float s = 0.f, ss = 0.f;
    const int total = N_NODES * HC;
    for (int i = blockIdx.x * 256 + threadIdx.x; i < total; i += gridDim.x * 256) {
        float v = g[i] / den[i >> 4] + gat_b[i & (HC - 1)];
        s += v; ss += v * v;
    }
    for (int m = 32; m >= 1; m >>= 1) { s += __shfl_xor(s, m); ss += __shfl_xor(ss, m); }
    __shared__ float sr[4], ssr[4];
    const int w = threadIdx.x >> 6;
    if ((threadIdx.x & 63) == 0) { sr[w] = s; ssr[w] = ss; }
    __syncthreads();
    if (threadIdx.x == 0) {
        atomicAdd(&stats[0], (double)(sr[0] + sr[1] + sr[2] + sr[3]));
        atomicAdd(&stats[1], (double)(ssr[0] + ssr[1] + ssr[2] + ssr[3]));
    }
}

// ---- apply LN1 + relu + linear(32->16) + stats for LN2 -----------------------
__global__ __launch_bounds__(256) void k_mid(
    const float* __restrict__ g, const float* __restrict__ den,
    const float* __restrict__ gat_b,
    const float* __restrict__ n1w, const float* __restrict__ n1b,
    const float* __restrict__ linW, const float* __restrict__ linb,
    const double* __restrict__ stats1, float* __restrict__ g2,
    double* __restrict__ stats2)
{
    __shared__ float Ws[HC * NC];
    __shared__ float rs[16][HC + 1];
    const int t = threadIdx.x;
    for (int i = t; i < HC * NC; i += 256) Ws[i] = linW[i];
    const double cnt = (double)N_NODES * HC;
    const double mud = stats1[0] / cnt;
    const float mu  = (float)mud;
    const float var = (float)(stats1[1] / cnt - mud * mud);
    const float inv = rsqrtf(var + EPS);
    const int n0 = blockIdx.x * 16;
    for (int i = t; i < 16 * HC; i += 256) {
        int r = i >> 5, j = i & 31;
        int n = n0 + r;
        float v;
        if (n < N_NODES)
            v = g[(size_t)n * HC + j] / den[(size_t)n * 2 + (j >> 4)] + gat_b[j];
        else v = mu;
        v = (v - mu) * inv * n1w[j] + n1b[j];
        rs[r][j] = fmaxf(v, 0.f);
    }
    __syncthreads();
    const int r = t >> 4, c = t & 15;
    const int n = n0 + r;
    float acc = linb[c];
#pragma unroll
    for (int j = 0; j < HC; ++j) acc += rs[r][j] * Ws[j * NC + c];
    float val = (n < N_NODES) ? acc : 0.f;
    if (n < N_NODES) g2[(size_t)n * NC + c] = acc;
    float s = val, ss = val * val;
    for (int m = 32; m >= 1; m >>= 1) { s += __shfl_xor(s, m); ss += __shfl_xor(ss, m); }
    __shared__ float sr[4], ssr[4];
    const int w = t >> 6;
    if ((t & 63) == 0) { sr[w] = s; ssr[w] = ss; }
    __syncthreads();
    if (t == 0) {
        atomicAdd(&stats2[0], (double)(sr[0] + sr[1] + sr[2] + sr[3]));
        atomicAdd(&stats2[1], (double)(ssr[0] + ssr[1] + ssr[2] + ssr[3]));
    }
}

// ---- apply LN2, residual + relu, update h and jk-max -------------------------
__global__ __launch_bounds__(256) void k_final(
    const float* __restrict__ g2, const float* __restrict__ n2w,
    const float* __restrict__ n2b, const double* __restrict__ stats2,
    float* __restrict__ h, float* __restrict__ jk)
{
    const int i = blockIdx.x * 256 + threadIdx.x;
    if (i >= N_NODES * NC) return;
    const double cnt = (double)N_NODES * NC;
    const double mud = stats2[0] / cnt;
    const float mu  = (float)mud;
    const float var = (float)(stats2[1] / cnt - mud * mud);
    const float inv = rsqrtf(var + EPS);
    const int c = i & (NC - 1);
    float v = (g2[i] - mu) * inv * n2w[c] + n2b[c];
    float hn = fmaxf(v + h[i], 0.f);
    h[i] = hn;
    jk[i] = fmaxf(jk[i], hn);
}

extern "C" void kernel_launch(void* const* d_in, const int* in_sizes, int n_in,
                              void* d_out, int out_size, void* d_ws, size_t ws_size,
                              hipStream_t stream)
{
    const float* x     = (const float*)d_in[0];
    const int*   eidx  = (const int*)d_in[1];
    const float* eattr = (const float*)d_in[2];
    const float* embW  = (const float*)d_in[3];
    const float* embB  = (const float*)d_in[4];
    const float* ln0w  = (const float*)d_in[5];
    const float* ln0b  = (const float*)d_in[6];
    const float* Wl    = (const float*)d_in[7];
    const float* bl    = (const float*)d_in[8];
    const float* Wr    = (const float*)d_in[9];
    const float* br    = (const float*)d_in[10];
    const float* We    = (const float*)d_in[11];
    const float* att   = (const float*)d_in[12];
    const float* gatb  = (const float*)d_in[13];
    const float* n1w   = (const float*)d_in[14];
    const float* n1b   = (const float*)d_in[15];
    const float* linW  = (const float*)d_in[16];
    const float* linb  = (const float*)d_in[17];
    const float* n2w   = (const float*)d_in[18];
    const float* n2b   = (const float*)d_in[19];
    float* out = (float*)d_out;

    // workspace: [stats 1KB (zeroed/layer)] [h][xl bf16][xr bf16][g][den][g2]
    char* ws = (char*)d_ws;
    double* stats = (double*)ws;
    char* p = ws + 1024;
    float* h  = (float*)p;          p += (size_t)N_NODES * NC * 4;
    unsigned short* xl = (unsigned short*)p; p += (size_t)N_NODES * HC * 2;
    unsigned short* xr = (unsigned short*)p; p += (size_t)N_NODES * HC * 2;
    float* g   = (float*)p;         p += (size_t)N_NODES * HC * 4;
    float* den = (float*)p;         p += (size_t)N_NODES * NH * 4;
    float* g2  = (float*)p;         p += (size_t)N_NODES * NC * 4;

    const int* srcp = eidx;
    const int* dstp = eidx + N_EDGES;

    k_embed<<<(N_NODES + 15) / 16, 256, 0, stream>>>(x, embW, embB, ln0w, ln0b, h, out);

    for (int l = 0; l < NL; ++l) {
        hipMemsetAsync(stats, 0, 1024, stream);
        k_trans<<<(N_NODES + 7) / 8, 256, 0, stream>>>(
            h, Wl + l * NC * HC, bl + l * HC, Wr + l * NC * HC, br + l * HC,
            att + l * HC, xl, xr, den, g);
        k_edge<<<(N_EDGES + 255) / 256, 256, 0, stream>>>(
            srcp, dstp, eattr, We + l * NED * HC, att + l * HC, xl, xr, den, g);
        k_stats1<<<1024, 256, 0, stream>>>(g, den, gatb + l * HC, stats);
        k_mid<<<(N_NODES + 15) / 16, 256, 0, stream>>>(
            g, den, gatb + l * HC, n1w + l * HC, n1b + l * HC,
            linW + l * HC * NC, linb + l * NC, stats, g2, stats + 2);
        k_final<<<(N_NODES * NC + 255) / 256, 256, 0, stream>>>(
            g2, n2w + l * NC, n2b + l * NC, stats + 2, h, out);
    }
}

// Round 3
// 1097.412 us; speedup vs baseline: 5.5998x; 5.5998x over previous
//
#include <hip/hip_runtime.h>

#define N_NODES 100000
#define N_EDGES 1600000
#define NF 128
#define NC 16
#define NH 2
#define HC 32   // NH*NC
#define NL 2
#define NED 4
#define EPS 1e-5f
#define NEG 0.2f

// ---- bf16 helpers (manual, RTN-even) -----------------------------------------
__device__ __forceinline__ unsigned short f2bf(float f) {
    unsigned int u = __float_as_uint(f);
    u += 0x7fffu + ((u >> 16) & 1u);
    return (unsigned short)(u >> 16);
}
__device__ __forceinline__ float bf2f(unsigned short u) {
    return __uint_as_float(((unsigned int)u) << 16);
}

// ---------------- embed: h = relu(node_LN(x @ W + b)) ; jk = h ----------------
__global__ __launch_bounds__(256) void k_embed(
    const float* __restrict__ x, const float* __restrict__ W,
    const float* __restrict__ b, const float* __restrict__ lnw,
    const float* __restrict__ lnb, float* __restrict__ h, float* __restrict__ jk)
{
    __shared__ float Ws[NF * NC];        // 8 KB
    __shared__ float xs[16][NF + 4];
    const int t = threadIdx.x;
    for (int i = t; i < NF * NC; i += 256) Ws[i] = W[i];
    const int n0 = blockIdx.x * 16;
    for (int i = t; i < 16 * NF; i += 256) {
        int r = i >> 7, f = i & (NF - 1);
        int n = n0 + r;
        xs[r][f] = (n < N_NODES) ? x[(size_t)n * NF + f] : 0.f;
    }
    __syncthreads();
    const int r = t >> 4;       // local node 0..15
    const int c = t & 15;       // channel
    const int n = n0 + r;
    float acc = b[c];
#pragma unroll 16
    for (int f = 0; f < NF; ++f) acc += xs[r][f] * Ws[f * NC + c];
    float s = acc;
    for (int m = 8; m >= 1; m >>= 1) s += __shfl_xor(s, m, 16);
    float mu = s * (1.f / 16.f);
    float d = acc - mu;
    float v = d * d;
    for (int m = 8; m >= 1; m >>= 1) v += __shfl_xor(v, m, 16);
    float inv = rsqrtf(v * (1.f / 16.f) + EPS);
    float out = fmaxf(d * inv * lnw[c] + lnb[c], 0.f);
    if (n < N_NODES) {
        h[(size_t)n * NC + c]  = out;
        jk[(size_t)n * NC + c] = out;
    }
}

// ---- per-layer: xl/xr transforms (bf16 out) + self-loop init of den/g --------
__global__ __launch_bounds__(256) void k_trans(
    const float* __restrict__ h, const float* __restrict__ Wl, const float* __restrict__ bl,
    const float* __restrict__ Wr, const float* __restrict__ br,
    const float* __restrict__ att,
    unsigned short* __restrict__ xl, unsigned short* __restrict__ xr,
    float* __restrict__ den, float* __restrict__ g)
{
    __shared__ float Wls[NC * HC], Wrs[NC * HC];
    __shared__ float atts[HC];
    __shared__ float hs[8][NC + 1];
    const int t = threadIdx.x;
    for (int i = t; i < NC * HC; i += 256) { Wls[i] = Wl[i]; Wrs[i] = Wr[i]; }
    if (t < HC) atts[t] = att[t];
    const int n0 = blockIdx.x * 8;
    for (int i = t; i < 8 * NC; i += 256) {
        int r = i >> 4, c = i & 15;
        int n = n0 + r;
        hs[r][c] = (n < N_NODES) ? h[(size_t)n * NC + c] : 0.f;
    }
    __syncthreads();
    const int r = t >> 5;     // local node 0..7
    const int j = t & 31;     // output col (head*16 + c)
    const int n = n0 + r;
    float al = bl[j], ar = br[j];
#pragma unroll
    for (int c = 0; c < NC; ++c) {
        float hv = hs[r][c];
        al += hv * Wls[c * HC + j];
        ar += hv * Wrs[c * HC + j];
    }
    // self-loop edge (src=dst=n, ew=0): logit per head via 16-lane reduce
    float m = al + ar;
    m = (m > 0.f) ? m : NEG * m;
    float p = m * atts[j];
    for (int k = 8; k >= 1; k >>= 1) p += __shfl_xor(p, k, 16);
    float exs = __expf(p);
    if (n < N_NODES) {
        xl[(size_t)n * HC + j] = f2bf(al);
        xr[(size_t)n * HC + j] = f2bf(ar);
        g[(size_t)n * HC + j]  = exs * al;          // init: self contribution
        if ((j & 15) == 0) den[(size_t)n * 2 + (j >> 4)] = exs;
    }
}

// ---- fused edge pass, 32 lanes per edge: logit via shfl, 1 atomic per lane ---
__global__ __launch_bounds__(256) void k_edge(
    const int* __restrict__ src, const int* __restrict__ dst,
    const float* __restrict__ eattr, const float* __restrict__ We,
    const float* __restrict__ att,
    const unsigned short* __restrict__ xl, const unsigned short* __restrict__ xr,
    float* __restrict__ den, float* __restrict__ g)
{
    __shared__ float Wes[NED * HC];
    __shared__ float atts[HC];
    const int t = threadIdx.x;
    if (t < NED * HC) Wes[t] = We[t];
    if (t < HC) atts[t] = att[t];
    __syncthreads();
    const int i = blockIdx.x * 256 + t;
    const int e = i >> 5;          // edge
    const int j = i & 31;          // channel (head*16 + c)
    if (e >= N_EDGES) return;
    const int s = src[e], d = dst[e];
    const float4 ea = *(const float4*)(eattr + (size_t)e * 4);
    const float xlv = bf2f(xl[(size_t)s * HC + j]);
    const float xrv = bf2f(xr[(size_t)d * HC + j]);
    float m = xlv + xrv
            + ea.x * Wes[j] + ea.y * Wes[HC + j]
            + ea.z * Wes[2 * HC + j] + ea.w * Wes[3 * HC + j];
    m = (m > 0.f) ? m : NEG * m;
    float p = m * atts[j];
    // per-head logit: sum over the 16 lanes of this head
    p += __shfl_xor(p, 1, 16);
    p += __shfl_xor(p, 2, 16);
    p += __shfl_xor(p, 4, 16);
    p += __shfl_xor(p, 8, 16);
    // logits tiny (std ~0.16): exp without segment-max is numerically identical
    const float eh = __expf(p);
    atomicAdd(&g[(size_t)d * HC + j], eh * xlv);   // 32 lanes -> one 128B line
    if ((j & 15) == 0) atomicAdd(&den[(size_t)d * 2 + (j >> 4)], eh);
}

// ---- graph-LN stats over (g/den + gat_b) -------------------------------------
__global__ __launch_bounds__(256) void k_stats1(
    const float* __restrict__ g, const float* __restrict__ den,
    const float* __restrict__ gat_b, double* __restrict__ stats)
{
    float s = 0.f, ss = 0.f;
    const int total = N_NODES * HC;
    for (int i = blockIdx.x * 256 + threadIdx.x; i < total; i += gridDim.x * 256) {
        float v = g[i] / den[i >> 4] + gat_b[i & (HC - 1)];
        s += v; ss += v * v;
    }
    for (int m = 32; m >= 1; m >>= 1) { s += __shfl_xor(s, m); ss += __shfl_xor(ss, m); }
    __shared__ float sr[4], ssr[4];
    const int w = threadIdx.x >> 6;
    if ((threadIdx.x & 63) == 0) { sr[w] = s; ssr[w] = ss; }
    __syncthreads();
    if (threadIdx.x == 0) {
        atomicAdd(&stats[0], (double)(sr[0] + sr[1] + sr[2] + sr[3]));
        atomicAdd(&stats[1], (double)(ssr[0] + ssr[1] + ssr[2] + ssr[3]));
    }
}

// ---- apply LN1 + relu + linear(32->16) + stats for LN2 -----------------------
__global__ __launch_bounds__(256) void k_mid(
    const float* __restrict__ g, const float* __restrict__ den,
    const float* __restrict__ gat_b,
    const float* __restrict__ n1w, const float* __restrict__ n1b,
    const float* __restrict__ linW, const float* __restrict__ linb,
    const double* __restrict__ stats1, float* __restrict__ g2,
    double* __restrict__ stats2)
{
    __shared__ float Ws[HC * NC];
    __shared__ float rs[16][HC + 1];
    const int t = threadIdx.x;
    for (int i = t; i < HC * NC; i += 256) Ws[i] = linW[i];
    const double cnt = (double)N_NODES * HC;
    const double mud = stats1[0] / cnt;
    const float mu  = (float)mud;
    const float var = (float)(stats1[1] / cnt - mud * mud);
    const float inv = rsqrtf(var + EPS);
    const int n0 = blockIdx.x * 16;
    for (int i = t; i < 16 * HC; i += 256) {
        int r = i >> 5, j = i & 31;
        int n = n0 + r;
        float v;
        if (n < N_NODES)
            v = g[(size_t)n * HC + j] / den[(size_t)n * 2 + (j >> 4)] + gat_b[j];
        else v = mu;
        v = (v - mu) * inv * n1w[j] + n1b[j];
        rs[r][j] = fmaxf(v, 0.f);
    }
    __syncthreads();
    const int r = t >> 4, c = t & 15;
    const int n = n0 + r;
    float acc = linb[c];
#pragma unroll
    for (int j = 0; j < HC; ++j) acc += rs[r][j] * Ws[j * NC + c];
    float val = (n < N_NODES) ? acc : 0.f;
    if (n < N_NODES) g2[(size_t)n * NC + c] = acc;
    float s = val, ss = val * val;
    for (int m = 32; m >= 1; m >>= 1) { s += __shfl_xor(s, m); ss += __shfl_xor(ss, m); }
    __shared__ float sr[4], ssr[4];
    const int w = t >> 6;
    if ((t & 63) == 0) { sr[w] = s; ssr[w] = ss; }
    __syncthreads();
    if (t == 0) {
        atomicAdd(&stats2[0], (double)(sr[0] + sr[1] + sr[2] + sr[3]));
        atomicAdd(&stats2[1], (double)(ssr[0] + ssr[1] + ssr[2] + ssr[3]));
    }
}

// ---- apply LN2, residual + relu, update h and jk-max -------------------------
__global__ __launch_bounds__(256) void k_final(
    const float* __restrict__ g2, const float* __restrict__ n2w,
    const float* __restrict__ n2b, const double* __restrict__ stats2,
    float* __restrict__ h, float* __restrict__ jk)
{
    const int i = blockIdx.x * 256 + threadIdx.x;
    if (i >= N_NODES * NC) return;
    const double cnt = (double)N_NODES * NC;
    const double mud = stats2[0] / cnt;
    const float mu  = (float)mud;
    const float var = (float)(stats2[1] / cnt - mud * mud);
    const float inv = rsqrtf(var + EPS);
    const int c = i & (NC - 1);
    float v = (g2[i] - mu) * inv * n2w[c] + n2b[c];
    float hn = fmaxf(v + h[i], 0.f);
    h[i] = hn;
    jk[i] = fmaxf(jk[i], hn);
}

extern "C" void kernel_launch(void* const* d_in, const int* in_sizes, int n_in,
                              void* d_out, int out_size, void* d_ws, size_t ws_size,
                              hipStream_t stream)
{
    const float* x     = (const float*)d_in[0];
    const int*   eidx  = (const int*)d_in[1];
    const float* eattr = (const float*)d_in[2];
    const float* embW  = (const float*)d_in[3];
    const float* embB  = (const float*)d_in[4];
    const float* ln0w  = (const float*)d_in[5];
    const float* ln0b  = (const float*)d_in[6];
    const float* Wl    = (const float*)d_in[7];
    const float* bl    = (const float*)d_in[8];
    const float* Wr    = (const float*)d_in[9];
    const float* br    = (const float*)d_in[10];
    const float* We    = (const float*)d_in[11];
    const float* att   = (const float*)d_in[12];
    const float* gatb  = (const float*)d_in[13];
    const float* n1w   = (const float*)d_in[14];
    const float* n1b   = (const float*)d_in[15];
    const float* linW  = (const float*)d_in[16];
    const float* linb  = (const float*)d_in[17];
    const float* n2w   = (const float*)d_in[18];
    const float* n2b   = (const float*)d_in[19];
    float* out = (float*)d_out;

    // workspace: [stats 1KB (zeroed/layer)] [h][xl bf16][xr bf16][g][den][g2]
    char* ws = (char*)d_ws;
    double* stats = (double*)ws;
    char* p = ws + 1024;
    float* h  = (float*)p;          p += (size_t)N_NODES * NC * 4;
    unsigned short* xl = (unsigned short*)p; p += (size_t)N_NODES * HC * 2;
    unsigned short* xr = (unsigned short*)p; p += (size_t)N_NODES * HC * 2;
    float* g   = (float*)p;         p += (size_t)N_NODES * HC * 4;
    float* den = (float*)p;         p += (size_t)N_NODES * NH * 4;
    float* g2  = (float*)p;         p += (size_t)N_NODES * NC * 4;

    const int* srcp = eidx;
    const int* dstp = eidx + N_EDGES;

    k_embed<<<(N_NODES + 15) / 16, 256, 0, stream>>>(x, embW, embB, ln0w, ln0b, h, out);

    for (int l = 0; l < NL; ++l) {
        hipMemsetAsync(stats, 0, 1024, stream);
        k_trans<<<(N_NODES + 7) / 8, 256, 0, stream>>>(
            h, Wl + l * NC * HC, bl + l * HC, Wr + l * NC * HC, br + l * HC,
            att + l * HC, xl, xr, den, g);
        k_edge<<<(N_EDGES * 32 + 255) / 256, 256, 0, stream>>>(
            srcp, dstp, eattr, We + l * NED * HC, att + l * HC, xl, xr, den, g);
        k_stats1<<<1024, 256, 0, stream>>>(g, den, gatb + l * HC, stats);
        k_mid<<<(N_NODES + 15) / 16, 256, 0, stream>>>(
            g, den, gatb + l * HC, n1w + l * HC, n1b + l * HC,
            linW + l * HC * NC, linb + l * NC, stats, g2, stats + 2);
        k_final<<<(N_NODES * NC + 255) / 256, 256, 0, stream>>>(
            g2, n2w + l * NC, n2b + l * NC, stats + 2, h, out);
    }
}